// Round 2
// baseline (77.205 us; speedup 1.0000x reference)
//
#include <hip/hip_runtime.h>
#include <math.h>

#define A_ATOMS 48
#define BLK     128
#define RADLEN  64     // 4 species * 16 SHFR
#define ANGLEN  320    // 10 pairs * 4 SHFA * 8 SHFZ
#define RCR_F 5.2f
#define RCA_F 3.5f

// cos/sin of SHFZ = k*pi/8 + pi/16, k=0..7
__device__ __constant__ float COSZ[8] = {
     0.98078528f,  0.83146961f,  0.55557023f,  0.19509032f,
    -0.19509032f, -0.55557023f, -0.83146961f, -0.98078528f};
__device__ __constant__ float SINZ[8] = {
     0.19509032f,  0.55557023f,  0.83146961f,  0.98078528f,
     0.98078528f,  0.83146961f,  0.55557023f,  0.19509032f};

__global__ __launch_bounds__(BLK) void aev_kernel(const int* __restrict__ species,
                                                  const float* __restrict__ coords,
                                                  float* __restrict__ out) {
    const int blk = blockIdx.x;
    const int n = blk / A_ATOMS;
    const int i = blk - n * A_ATOMS;
    const int tid = threadIdx.x;

    __shared__ float sx[A_ATOMS], sy[A_ATOMS], sz_[A_ATOMS];
    __shared__ int   sspec[A_ATOMS];
    __shared__ int   rr_cnt, nb_cnt;
    // radial cutoff list (d <= 5.2): distance, premultiplied 0.25*fc, species
    __shared__ float rr_d[A_ATOMS], rr_fc[A_ATOMS];
    __shared__ int   rr_s[A_ATOMS];
    // angular cutoff list (d <= 3.5)
    __shared__ float nb_dx[A_ATOMS], nb_dy[A_ATOMS], nb_dz[A_ATOMS];
    __shared__ float nb_d[A_ATOMS], nb_fc[A_ATOMS];
    __shared__ int   nb_s[A_ATOMS];
    // pair records (one chunk)
    __shared__ float pr_x[BLK], pr_sn[BLK], pr_dh[BLK], pr_b2[BLK];
    __shared__ int   pr_pi[BLK];

    // ---- phase A: stage molecule ----
    if (tid < A_ATOMS) {
        const float* c = coords + ((size_t)n * A_ATOMS + tid) * 3;
        sx[tid]  = c[0];
        sy[tid]  = c[1];
        sz_[tid] = c[2];
        sspec[tid] = species[n * A_ATOMS + tid];
    }
    if (tid == 0) { rr_cnt = 0; nb_cnt = 0; }
    __syncthreads();

    const float xi = sx[i], yi = sy[i], zi = sz_[i];
    const bool  vi = (sspec[i] >= 0);

    // ---- phase A2: distances + compacted cutoff lists (fc computed ONCE per j) ----
    if (tid < A_ATOMS) {
        const int j = tid;
        if (vi && j != i && sspec[j] >= 0) {
            float dx = xi - sx[j], dy = yi - sy[j], dz = zi - sz_[j];
            float d2 = dx*dx + dy*dy + dz*dz;
            float d  = (d2 > 0.f) ? sqrtf(d2) : 1.0f;   // ref: where(d2>0, d2, 1)
            if (d <= RCR_F) {
                int s = atomicAdd(&rr_cnt, 1);
                rr_d[s]  = d;
                rr_fc[s] = 0.25f * (0.5f * __cosf(d * (float)(M_PI / 5.2)) + 0.5f);
                rr_s[s]  = sspec[j];
            }
            if (d <= RCA_F) {
                int s = atomicAdd(&nb_cnt, 1);
                nb_dx[s] = dx; nb_dy[s] = dy; nb_dz[s] = dz;
                nb_d[s]  = d;
                nb_fc[s] = 0.5f * __cosf(d * (float)(M_PI / 3.5)) + 0.5f;
                nb_s[s]  = sspec[j];
            }
        }
    }
    __syncthreads();

    float* o = out + (size_t)blk * (RADLEN + ANGLEN);

    // ---- radial: lanes 0..63 own (species, shfr) bins; no atomics ----
    if (tid < RADLEN) {
        const int   s    = tid >> 4;
        const float shfr = 0.9f + 0.26875f * (float)(tid & 15);
        float acc = 0.f;
        const int Mr = rr_cnt;
        for (int m = 0; m < Mr; ++m) {
            if (rr_s[m] == s) {
                float e = rr_d[m] - shfr;
                acc += rr_fc[m] * __expf(-16.f * e * e);
            }
        }
        o[tid] = acc;
    }

    // ---- angular feature ownership: lane owns 3 features in registers ----
    float accf[3] = {0.f, 0.f, 0.f};
    int   pik[3];
    float czk[3], szk[3], shk[3];
    #pragma unroll
    for (int k = 0; k < 3; ++k) {
        int f = tid * 3 + k;
        if (f < ANGLEN) {
            pik[k] = f >> 5;
            int aa = (f >> 3) & 3, zz = f & 7;
            czk[k] = COSZ[zz]; szk[k] = SINZ[zz];
            shk[k] = 0.9f + 0.65f * (float)aa;
        } else {
            pik[k] = -1; czk[k] = 0.f; szk[k] = 0.f; shk[k] = 0.f;
        }
    }

    // ---- angular: chunked pair records -> broadcast scan ----
    const int M = nb_cnt;
    const int P = (M * (M - 1)) >> 1;
    for (int pb = 0; pb < P; pb += BLK) {
        const int p = pb + tid;
        if (p < P) {
            int a = (int)((1.f + sqrtf(1.f + 8.f * (float)p)) * 0.5f);
            while ((a * (a - 1)) / 2 > p) --a;
            while (((a + 1) * a) / 2 <= p) ++a;
            const int b = p - (a * (a - 1)) / 2;

            const float dj = nb_d[a], dk = nb_d[b];
            const float dotp = nb_dx[a]*nb_dx[b] + nb_dy[a]*nb_dy[b] + nb_dz[a]*nb_dz[b];
            const float x  = 0.95f * dotp / fmaxf(dj * dk, 1e-10f);
            pr_x[tid]  = x;
            pr_sn[tid] = sqrtf(fmaxf(0.f, 1.f - x * x));
            pr_dh[tid] = 0.5f * (dj + dk);
            pr_b2[tid] = 2.f * nb_fc[a] * nb_fc[b];
            const int sj = nb_s[a], sk = nb_s[b];
            const int lo = (sj < sk) ? sj : sk;
            const int hi = (sj < sk) ? sk : sj;
            pr_pi[tid] = (lo * (9 - lo)) / 2 + (hi - lo);
        }
        __syncthreads();
        const int cnt = (P - pb < BLK) ? (P - pb) : BLK;
        for (int m = 0; m < cnt; ++m) {
            const float x  = pr_x[m];     // broadcast reads: all lanes same addr
            const float sn = pr_sn[m];
            const float dh = pr_dh[m];
            const float b2 = pr_b2[m];
            const int   pi = pr_pi[m];
            #pragma unroll
            for (int k = 0; k < 3; ++k) {
                if (pi == pik[k]) {
                    float c = x * czk[k] + sn * szk[k];   // cos(angle - shfz)
                    float t = 0.5f * (1.f + c);
                    float t2 = t*t, t4 = t2*t2, t8 = t4*t4, t16 = t8*t8;
                    float e = dh - shk[k];
                    accf[k] += b2 * __expf(-8.f * e * e) * (t16 * t16);  // t^32
                }
            }
        }
        __syncthreads();
    }

    // ---- write angular from registers (each feature owned by exactly one lane) ----
    #pragma unroll
    for (int k = 0; k < 3; ++k) {
        int f = tid * 3 + k;
        if (f < ANGLEN) o[RADLEN + f] = accf[k];
    }
}

extern "C" void kernel_launch(void* const* d_in, const int* in_sizes, int n_in,
                              void* d_out, int out_size, void* d_ws, size_t ws_size,
                              hipStream_t stream) {
    const int*   species = (const int*)d_in[0];
    const float* coords  = (const float*)d_in[1];
    float*       out     = (float*)d_out;
    const int NA = in_sizes[0];        // N*A = 1536
    aev_kernel<<<dim3(NA), dim3(BLK), 0, stream>>>(species, coords, out);
}

// Round 3
// 70.331 us; speedup vs baseline: 1.0977x; 1.0977x over previous
//
#include <hip/hip_runtime.h>
#include <math.h>

#define A_ATOMS 48
#define BLK     128
#define RADLEN  64     // 4 species * 16 SHFR
#define ANGLEN  320    // 10 pairs * 4 SHFA * 8 SHFZ

__global__ __launch_bounds__(BLK) void aev_kernel(const int* __restrict__ species,
                                                  const float* __restrict__ coords,
                                                  float* __restrict__ out) {
    const int blk = blockIdx.x;
    const int n = blk / A_ATOMS;
    const int i = blk - n * A_ATOMS;
    const int tid = threadIdx.x;

    __shared__ float sx[A_ATOMS], sy[A_ATOMS], sz_[A_ATOMS];
    __shared__ int   sspec[A_ATOMS];
    __shared__ int   rr_cnt, nb_cnt;
    __shared__ float rr_d[A_ATOMS], rr_fc[A_ATOMS];   // fc premultiplied by 0.25
    __shared__ int   rr_s[A_ATOMS];
    __shared__ float4 nb_v[A_ATOMS];                  // dx,dy,dz,d
    __shared__ float  nb_fc[A_ATOMS];
    __shared__ int    nb_s[A_ATOMS];
    __shared__ float  afeat[ANGLEN];

    // ---- stage molecule + zero accumulators ----
    if (tid < A_ATOMS) {
        const float* c = coords + ((size_t)n * A_ATOMS + tid) * 3;
        sx[tid]  = c[0];
        sy[tid]  = c[1];
        sz_[tid] = c[2];
        sspec[tid] = species[n * A_ATOMS + tid];
    }
    for (int t = tid; t < ANGLEN; t += BLK) afeat[t] = 0.f;
    if (tid == 0) { rr_cnt = 0; nb_cnt = 0; }
    __syncthreads();

    const float xi = sx[i], yi = sy[i], zi = sz_[i];
    const bool  vi = (sspec[i] >= 0);

    // ---- distances + compacted cutoff lists ----
    if (tid < A_ATOMS) {
        const int j = tid;
        if (vi && j != i && sspec[j] >= 0) {
            float dx = xi - sx[j], dy = yi - sy[j], dz = zi - sz_[j];
            float d2 = dx*dx + dy*dy + dz*dz;
            float d  = (d2 > 0.f) ? sqrtf(d2) : 1.0f;   // ref: where(d2>0, d2, 1)
            if (d <= 5.2f) {
                int s = atomicAdd(&rr_cnt, 1);
                rr_d[s]  = d;
                rr_fc[s] = 0.25f * (0.5f * __cosf(d * (float)(M_PI / 5.2)) + 0.5f);
                rr_s[s]  = sspec[j];
            }
            if (d <= 3.5f) {
                int s = atomicAdd(&nb_cnt, 1);
                nb_v[s]  = make_float4(dx, dy, dz, d);
                nb_fc[s] = 0.5f * __cosf(d * (float)(M_PI / 3.5)) + 0.5f;
                nb_s[s]  = sspec[j];
            }
        }
    }
    __syncthreads();

    float* o = out + (size_t)blk * (RADLEN + ANGLEN);

    // ---- wave 1: radial bins (64 lanes own 64 features), direct coalesced write ----
    if (tid >= 64) {
        const int bin = tid - 64;
        const int s   = bin >> 4;
        const float shfr = 0.9f + 0.26875f * (float)(bin & 15);
        float acc = 0.f;
        const int Mr = rr_cnt;
        for (int m = 0; m < Mr; ++m) {
            if (rr_s[m] == s) {
                float e = rr_d[m] - shfr;
                acc += rr_fc[m] * __expf(-16.f * e * e);
            }
        }
        o[bin] = acc;
    }

    // ---- angular: half-wave per pair record, 32 feature-lanes each ----
    const int ff = tid & 31;            // feature within pair-class
    const int zz = ff & 7, aa = ff >> 3;
    float cz, szn;
    __sincosf((float)zz * (float)(M_PI / 8.0) + (float)(M_PI / 16.0), &szn, &cz);
    const float shfa = 0.9f + 0.65f * (float)aa;

    const int M = nb_cnt;
    const int P = (M * (M - 1)) >> 1;
    const int h = tid >> 5;             // half-wave id 0..3
    for (int p = h; p < P; p += 4) {
        // closed-form decode p -> (a,b), a>b (single-step corrections)
        int a = (int)((1.f + sqrtf((float)(1 + 8 * p))) * 0.5f);
        if ((a * (a - 1)) / 2 > p) --a;
        if (((a + 1) * a) / 2 <= p) ++a;
        const int b = p - (a * (a - 1)) / 2;

        const float4 va = nb_v[a], vb = nb_v[b];
        const float dj = va.w, dk = vb.w;
        const float dotp = va.x*vb.x + va.y*vb.y + va.z*vb.z;
        const float x  = 0.95f * dotp / fmaxf(dj * dk, 1e-10f);
        const float sn = sqrtf(fmaxf(0.f, 1.f - x * x));
        const float dh = 0.5f * (dj + dk);
        const float b2 = 2.f * nb_fc[a] * nb_fc[b];
        const int sj = nb_s[a], sk = nb_s[b];
        const int lo = (sj < sk) ? sj : sk;
        const int hi = (sj < sk) ? sk : sj;
        const int pidx = (lo * (9 - lo)) / 2 + (hi - lo);

        // this lane's feature of the pair
        const float c = x * cz + sn * szn;           // cos(angle - shfz)
        const float t = 0.5f + 0.5f * c;
        const float t2 = t*t, t4 = t2*t2, t8 = t4*t4, t16 = t8*t8;
        const float e = dh - shfa;
        const float val = b2 * __expf(-8.f * e * e) * (t16 * t16);   // t^32
        atomicAdd(&afeat[pidx * 32 + ff], val);      // 32 consecutive banks: conflict-free
    }
    __syncthreads();

    // ---- coalesced angular write ----
    for (int t = tid; t < ANGLEN; t += BLK) o[RADLEN + t] = afeat[t];
}

extern "C" void kernel_launch(void* const* d_in, const int* in_sizes, int n_in,
                              void* d_out, int out_size, void* d_ws, size_t ws_size,
                              hipStream_t stream) {
    const int*   species = (const int*)d_in[0];
    const float* coords  = (const float*)d_in[1];
    float*       out     = (float*)d_out;
    const int NA = in_sizes[0];        // N*A = 1536
    aev_kernel<<<dim3(NA), dim3(BLK), 0, stream>>>(species, coords, out);
}